// Round 2
// baseline (793.887 us; speedup 1.0000x reference)
//
#include <hip/hip_runtime.h>

// GCN 2-layer: N=250000 nodes, E=5,000,000 edges, feats 5 -> 16 -> 4.
// out = relu(gcn(relu(gcn(x, W1, b1)), W2, b2))
// gcn(x,W,b): xw = x@W; deg = indeg+1 (self loop); dinv = rsqrt(deg);
//   out[n] = dinv[n] * ( dinv[n]*xw[n] + sum_{s->n} dinv[s]*xw[s] ) + b

constexpr int F0 = 5, F1 = 16, F2 = 4;

__global__ void zero_counts(int* __restrict__ cnt, int n) {
    int i = blockIdx.x * blockDim.x + threadIdx.x;
    if (i < n) cnt[i] = 0;
}

__global__ void count_deg(const int* __restrict__ dst, int* __restrict__ cnt, int ne) {
    int e = blockIdx.x * blockDim.x + threadIdx.x;
    if (e < ne) atomicAdd(&cnt[dst[e]], 1);
}

// in-place: reads int count, writes float dinv to the SAME buffer (elementwise, safe)
__global__ void compute_dinv(int* __restrict__ cnt_in_dinv_out, int n) {
    int i = blockIdx.x * blockDim.x + threadIdx.x;
    if (i >= n) return;
    int c = cnt_in_dinv_out[i];
    reinterpret_cast<float*>(cnt_in_dinv_out)[i] = rsqrtf((float)(c + 1));
}

// y1 = dinv * (x @ W1); acc1 = y1 (self-loop seed)
__global__ void l1_transform(const float* __restrict__ x, const float* __restrict__ W1,
                             const float* __restrict__ dinv, float* __restrict__ y1,
                             float* __restrict__ acc1, int n) {
    __shared__ float w[F0 * F1];
    if (threadIdx.x < F0 * F1) w[threadIdx.x] = W1[threadIdx.x];
    __syncthreads();
    int i = blockIdx.x * blockDim.x + threadIdx.x;
    if (i >= n) return;
    float xv[F0];
#pragma unroll
    for (int k = 0; k < F0; k++) xv[k] = x[i * F0 + k];
    float di = dinv[i];
#pragma unroll
    for (int j = 0; j < F1; j++) {
        float v = 0.f;
#pragma unroll
        for (int k = 0; k < F0; k++) v += xv[k] * w[k * F1 + j];
        v *= di;
        y1[i * F1 + j] = v;
        acc1[i * F1 + j] = v;
    }
}

// one thread per (edge, j): acc1[dst*16+j] += y1[src*16+j]
__global__ void scatter1(const int* __restrict__ src, const int* __restrict__ dst,
                         const float* __restrict__ y1, float* __restrict__ acc1, int ne) {
    int t = blockIdx.x * blockDim.x + threadIdx.x;
    int e = t >> 4;
    int j = t & 15;
    if (e >= ne) return;
    int s = src[e], d = dst[e];
    atomicAdd(&acc1[d * F1 + j], y1[s * F1 + j]);
}

// h = relu(dinv*acc1 + b1); y2 = dinv*(h@W2); acc2 = y2
__global__ void l2_transform(const float* __restrict__ acc1, const float* __restrict__ b1,
                             const float* __restrict__ W2, const float* __restrict__ dinv,
                             float* __restrict__ y2, float* __restrict__ acc2, int n) {
    __shared__ float w[F1 * F2];
    __shared__ float bb[F1];
    if (threadIdx.x < F1 * F2) w[threadIdx.x] = W2[threadIdx.x];
    if (threadIdx.x < F1) bb[threadIdx.x] = b1[threadIdx.x];
    __syncthreads();
    int i = blockIdx.x * blockDim.x + threadIdx.x;
    if (i >= n) return;
    float di = dinv[i];
    float h[F1];
#pragma unroll
    for (int k = 0; k < F1; k++) {
        float v = di * acc1[i * F1 + k] + bb[k];
        h[k] = v > 0.f ? v : 0.f;
    }
#pragma unroll
    for (int j = 0; j < F2; j++) {
        float v = 0.f;
#pragma unroll
        for (int k = 0; k < F1; k++) v += h[k] * w[k * F2 + j];
        v *= di;
        y2[i * F2 + j] = v;
        acc2[i * F2 + j] = v;
    }
}

// one thread per (edge, j): acc2[dst*4+j] += y2[src*4+j]
__global__ void scatter2(const int* __restrict__ src, const int* __restrict__ dst,
                         const float* __restrict__ y2, float* __restrict__ acc2, int ne) {
    int t = blockIdx.x * blockDim.x + threadIdx.x;
    int e = t >> 2;
    int j = t & 3;
    if (e >= ne) return;
    int s = src[e], d = dst[e];
    atomicAdd(&acc2[d * F2 + j], y2[s * F2 + j]);
}

__global__ void finish(const float* __restrict__ acc2, const float* __restrict__ b2,
                       const float* __restrict__ dinv, float* __restrict__ out, int n) {
    int i = blockIdx.x * blockDim.x + threadIdx.x;
    if (i >= n) return;
    float di = dinv[i];
    float4 a = reinterpret_cast<const float4*>(acc2)[i];
    float4 r;
    r.x = fmaxf(di * a.x + b2[0], 0.f);
    r.y = fmaxf(di * a.y + b2[1], 0.f);
    r.z = fmaxf(di * a.z + b2[2], 0.f);
    r.w = fmaxf(di * a.w + b2[3], 0.f);
    reinterpret_cast<float4*>(out)[i] = r;
}

extern "C" void kernel_launch(void* const* d_in, const int* in_sizes, int n_in,
                              void* d_out, int out_size, void* d_ws, size_t ws_size,
                              hipStream_t stream) {
    const float* x  = (const float*)d_in[0];
    const int*   ei = (const int*)d_in[1];   // [2, E] int32
    const float* W1 = (const float*)d_in[2];
    const float* b1 = (const float*)d_in[3];
    const float* W2 = (const float*)d_in[4];
    const float* b2 = (const float*)d_in[5];
    float* out = (float*)d_out;

    const int n  = in_sizes[0] / F0;   // 250000
    const int ne = in_sizes[1] / 2;    // 5000000
    const int* src = ei;
    const int* dst = ei + ne;

    // workspace layout (bytes), 256B-aligned offsets; total ~37 MB
    char* ws = (char*)d_ws;
    size_t off = 0;
    int*   cnt  = (int*)(ws + off);                       // n*4 = 1 MB (becomes dinv in-place)
    float* dinv = (float*)cnt;
    off += ((size_t)n * 4 + 255) & ~255ull;
    float* y1   = (float*)(ws + off);                     // n*16*4 = 16 MB
    off += ((size_t)n * F1 * 4 + 255) & ~255ull;
    float* acc1 = (float*)(ws + off);                     // 16 MB
    off += ((size_t)n * F1 * 4 + 255) & ~255ull;
    float* y2   = (float*)(ws + off);                     // n*4*4 = 4 MB
    off += ((size_t)n * F2 * 4 + 255) & ~255ull;
    float* acc2 = (float*)(ws + off);                     // 4 MB

    const int B = 256;
    zero_counts<<<(n + B - 1) / B, B, 0, stream>>>(cnt, n);
    count_deg<<<(ne + B - 1) / B, B, 0, stream>>>(dst, cnt, ne);
    compute_dinv<<<(n + B - 1) / B, B, 0, stream>>>(cnt, n);

    l1_transform<<<(n + B - 1) / B, B, 0, stream>>>(x, W1, dinv, y1, acc1, n);
    {
        long long total = (long long)ne * F1;  // 80M threads
        scatter1<<<(int)((total + B - 1) / B), B, 0, stream>>>(src, dst, y1, acc1, ne);
    }
    l2_transform<<<(n + B - 1) / B, B, 0, stream>>>(acc1, b1, W2, dinv, y2, acc2, n);
    {
        long long total = (long long)ne * F2;  // 20M threads
        scatter2<<<(int)((total + B - 1) / B), B, 0, stream>>>(src, dst, y2, acc2, ne);
    }
    finish<<<(n + B - 1) / B, B, 0, stream>>>(acc2, b2, dinv, out, n);
}